// Round 1
// baseline (431.926 us; speedup 1.0000x reference)
//
#include <hip/hip_runtime.h>

typedef __bf16 bf16;
typedef bf16 bf16x4 __attribute__((ext_vector_type(4)));
typedef bf16 bf16x8 __attribute__((ext_vector_type(8)));
typedef float floatx4 __attribute__((ext_vector_type(4)));

#define B_ 8
#define S_ 2048
#define I_ 1024
#define H_ 64
#define NEG_INF_ -1000000000.0f

// ---------------- Kernel A: fold scale + convert weights to bf16 ----------------
// Wc[192][1024] bf16: rows 0-63 = Wq*0.125, 64-127 = Wk, 128-191 = Wv
__global__ void conv_w(const float* __restrict__ Wq, const float* __restrict__ bq,
                       const float* __restrict__ Wk, const float* __restrict__ bk,
                       const float* __restrict__ Wv, const float* __restrict__ bv,
                       bf16* __restrict__ Wc, float* __restrict__ bc) {
    int idx = blockIdx.x * 256 + threadIdx.x;   // 0 .. 192*1024-1
    int n = idx >> 10, i = idx & 1023;
    float v;
    if (n < 64)       v = Wq[n * I_ + i] * 0.125f;
    else if (n < 128) v = Wk[(n - 64) * I_ + i];
    else              v = Wv[(n - 128) * I_ + i];
    Wc[idx] = (bf16)v;
    if (idx < 192) {
        float bb = (idx < 64) ? bq[idx] * 0.125f
                 : (idx < 128) ? bk[idx - 64] : bv[idx - 128];
        bc[idx] = bb;
    }
}

// ---------------- Kernel B: QKV projection GEMM (MFMA bf16) ----------------
// Block: 256 thr (4 waves), tile M=32 x N=192, K-loop BK=32. Grid 512.
// Waves 0,1: rows 0-15/16-31, N 0-95.  Waves 2,3: same rows, N 96-191.
// Outputs: Qd[b][s][h] bf16 (pre-scaled by 1/8), Kd[b][s][h] bf16, Vtd[b][h][s] bf16.
__global__ __launch_bounds__(256) void qkv_gemm(const float* __restrict__ X,
                                                const bf16* __restrict__ Wc,
                                                const float* __restrict__ bc,
                                                bf16* __restrict__ Qd,
                                                bf16* __restrict__ Kd,
                                                bf16* __restrict__ Vtd) {
    __shared__ bf16 Xs[32 * 40];    // pad 32->40 (row stride 80B, 16B-aligned)
    __shared__ bf16 Ws[192 * 40];

    int tid = threadIdx.x;
    int w = tid >> 6, lane = tid & 63;
    int n = lane & 15, g = lane >> 4;
    int m0 = blockIdx.x * 32;
    int rh = w & 1;                 // row half (0/1)
    int nw = (w >> 1) * 96;         // N base (0/96)

    floatx4 zero4 = {0.0f, 0.0f, 0.0f, 0.0f};
    floatx4 acc[6];
#pragma unroll
    for (int t = 0; t < 6; ++t) acc[t] = zero4;

    int xrow = tid >> 3, xq = tid & 7;   // X staging: 32 rows x 8 float4
    const float* xsrc = X + (size_t)(m0 + xrow) * I_ + xq * 4;
    bf16* xdst = Xs + xrow * 40 + xq * 4;

    for (int kk0 = 0; kk0 < I_; kk0 += 32) {
        // stage X tile (32x32 fp32 -> bf16)
        float4 xv = *(const float4*)(xsrc + kk0);
        bf16x4 xb;
        xb[0] = (bf16)xv.x; xb[1] = (bf16)xv.y; xb[2] = (bf16)xv.z; xb[3] = (bf16)xv.w;
        *(bf16x4*)xdst = xb;
        // stage W tile (192x32 bf16): 768 16B-chunks, 3 per thread
#pragma unroll
        for (int i = 0; i < 3; ++i) {
            int cid = i * 256 + tid;
            int wrow = cid >> 2, wc = cid & 3;
            *(bf16x8*)(Ws + wrow * 40 + wc * 8) =
                *(const bf16x8*)(Wc + (size_t)wrow * I_ + kk0 + wc * 8);
        }
        __syncthreads();

        // A-frag: A[m=lane&15][kk=g*8+j]
        bf16x8 xa = *(bf16x8*)(Xs + (rh * 16 + n) * 40 + g * 8);
#pragma unroll
        for (int nt = 0; nt < 6; ++nt) {
            bf16x8 wb = *(bf16x8*)(Ws + (nw + nt * 16 + n) * 40 + g * 8);
            acc[nt] = __builtin_amdgcn_mfma_f32_16x16x32_bf16(xa, wb, acc[nt], 0, 0, 0);
        }
        __syncthreads();
    }

    // epilogue: C/D layout col=lane&15, row=g*4+reg
    int b = m0 >> 11;                          // 32 | 2048 so whole block same b
    int sb = (m0 & 2047) + rh * 16 + g * 4;    // seq base for this lane's 4 rows
#pragma unroll
    for (int nt = 0; nt < 6; ++nt) {
        int ng = nw + nt * 16 + n;
        float bias = bc[ng];
        if (ng < 64) {
#pragma unroll
            for (int r = 0; r < 4; ++r)
                Qd[(size_t)(b * S_ + sb + r) * H_ + ng] = (bf16)(acc[nt][r] + bias);
        } else if (ng < 128) {
#pragma unroll
            for (int r = 0; r < 4; ++r)
                Kd[(size_t)(b * S_ + sb + r) * H_ + (ng - 64)] = (bf16)(acc[nt][r] + bias);
        } else {
            bf16x4 pk;
#pragma unroll
            for (int r = 0; r < 4; ++r) pk[r] = (bf16)(acc[nt][r] + bias);
            *(bf16x4*)(Vtd + (size_t)(b * H_ + (ng - 128)) * S_ + sb) = pk;
        }
    }
}

// ---------------- Kernel C: flash attention with online softmax ----------------
// Grid 256 (8 b x 32 q-tiles of 64). 4 waves; wave w owns q rows q0+16w..+15.
// K-tile 128. Q frags in regs; K/V staged to padded LDS; P via LDS (C->A layout).
__global__ __launch_bounds__(256) void attn(const bf16* __restrict__ Qd,
                                            const bf16* __restrict__ Kd,
                                            const bf16* __restrict__ Vtd,
                                            const int* __restrict__ mask,
                                            float* __restrict__ out) {
    __shared__ bf16 Ks[128 * 72];   // K rows [kidx][h], stride 72 (144B)
    __shared__ bf16 Vs[64 * 136];   // V^T rows [h][kidx], stride 136 (272B)
    __shared__ bf16 Ps[64 * 136];   // P rows [q][kidx], stride 136

    int tid = threadIdx.x;
    int w = tid >> 6, lane = tid & 63;
    int n = lane & 15, g = lane >> 4;
    int b = blockIdx.x >> 5;
    int q0 = (blockIdx.x & 31) * 64;

    // Q A-frags (Q already scaled by 1/8): A[m=lane&15][kk=g*8+j], h = kk (+32)
    const bf16* qptr = Qd + (size_t)(b * S_ + q0 + w * 16 + n) * H_ + g * 8;
    bf16x8 qa0 = *(const bf16x8*)qptr;
    bf16x8 qa1 = *(const bf16x8*)(qptr + 32);

    floatx4 zero4 = {0.0f, 0.0f, 0.0f, 0.0f};
    floatx4 o[4];
#pragma unroll
    for (int t = 0; t < 4; ++t) o[t] = zero4;
    float m_i[4], l_i[4];
#pragma unroll
    for (int r = 0; r < 4; ++r) { m_i[r] = -INFINITY; l_i[r] = 0.0f; }

    int krow = tid >> 1, kc = (tid & 1) * 4;   // K staging: 128 rows x 8 chunks
    int vrow = tid >> 2, vc = (tid & 3) * 4;   // V staging: 64 rows x 16 chunks

    for (int kt = 0; kt < S_ / 128; ++kt) {
        // ---- stage K tile (128x64 bf16 = 16KB) ----
        const bf16* ksrc = Kd + (size_t)(b * S_ + kt * 128 + krow) * H_;
#pragma unroll
        for (int i = 0; i < 4; ++i)
            *(bf16x8*)(Ks + krow * 72 + (kc + i) * 8) = *(const bf16x8*)(ksrc + (kc + i) * 8);
        // ---- stage V^T tile (64x128 bf16 = 16KB) ----
        const bf16* vsrc = Vtd + (size_t)(b * H_ + vrow) * S_ + kt * 128;
#pragma unroll
        for (int i = 0; i < 4; ++i)
            *(bf16x8*)(Vs + vrow * 136 + (vc + i) * 8) = *(const bf16x8*)(vsrc + (vc + i) * 8);
        __syncthreads();

        // ---- S = Q K^T (scaled): 8 n-tiles of 16 cols ----
        floatx4 s[8];
#pragma unroll
        for (int nt = 0; nt < 8; ++nt) {
            const bf16* kb = Ks + (nt * 16 + n) * 72 + g * 8;   // B[n=lane&15][kk=g*8+j]
            floatx4 a = zero4;
            a = __builtin_amdgcn_mfma_f32_16x16x32_bf16(qa0, *(const bf16x8*)kb, a, 0, 0, 0);
            a = __builtin_amdgcn_mfma_f32_16x16x32_bf16(qa1, *(const bf16x8*)(kb + 32), a, 0, 0, 0);
            s[nt] = a;
        }

        // ---- mask: s layout col=lane&15 (k), row=g*4+reg (q) ----
        const int* mbase = mask + (size_t)(b * S_ + q0 + w * 16 + g * 4) * S_ + kt * 128 + n;
#pragma unroll
        for (int r = 0; r < 4; ++r) {
#pragma unroll
            for (int nt = 0; nt < 8; ++nt) {
                int mv = mbase[(size_t)r * S_ + nt * 16];
                if (mv == 0) s[nt][r] = NEG_INF_;
            }
        }

        // ---- online softmax per q-row (row state shared by 16-lane group) ----
#pragma unroll
        for (int r = 0; r < 4; ++r) {
            float tm = s[0][r];
#pragma unroll
            for (int nt = 1; nt < 8; ++nt) tm = fmaxf(tm, s[nt][r]);
#pragma unroll
            for (int off = 1; off < 16; off <<= 1) tm = fmaxf(tm, __shfl_xor(tm, off, 64));
            float mn = fmaxf(m_i[r], tm);
            float alpha = __expf(m_i[r] - mn);   // m_i=-inf first iter -> alpha=0
            m_i[r] = mn;
            float rs = 0.0f;
#pragma unroll
            for (int nt = 0; nt < 8; ++nt) {
                float p = __expf(s[nt][r] - mn);
                s[nt][r] = p;
                rs += p;
            }
#pragma unroll
            for (int off = 1; off < 16; off <<= 1) rs += __shfl_xor(rs, off, 64);
            l_i[r] = l_i[r] * alpha + rs;
#pragma unroll
            for (int ht = 0; ht < 4; ++ht) o[ht][r] *= alpha;
        }

        // ---- P: C-layout -> LDS -> A-layout (m120 pattern) ----
#pragma unroll
        for (int r = 0; r < 4; ++r)
#pragma unroll
            for (int nt = 0; nt < 8; ++nt)
                Ps[(w * 16 + g * 4 + r) * 136 + nt * 16 + n] = (bf16)s[nt][r];
        __syncthreads();

        // ---- O += P V : 4 K-steps of 32, 4 h-tiles ----
#pragma unroll
        for (int k0 = 0; k0 < 4; ++k0) {
            bf16x8 pa = *(bf16x8*)(Ps + (w * 16 + n) * 136 + k0 * 32 + g * 8);
#pragma unroll
            for (int ht = 0; ht < 4; ++ht) {
                bf16x8 vb = *(bf16x8*)(Vs + (ht * 16 + n) * 136 + k0 * 32 + g * 8);
                o[ht] = __builtin_amdgcn_mfma_f32_16x16x32_bf16(pa, vb, o[ht], 0, 0, 0);
            }
        }
        __syncthreads();
    }

    // ---- epilogue: out fp32 [b][s][h] ----
#pragma unroll
    for (int ht = 0; ht < 4; ++ht)
#pragma unroll
        for (int r = 0; r < 4; ++r)
            out[(size_t)(b * S_ + q0 + w * 16 + g * 4 + r) * H_ + ht * 16 + n] =
                o[ht][r] / l_i[r];
}

extern "C" void kernel_launch(void* const* d_in, const int* in_sizes, int n_in,
                              void* d_out, int out_size, void* d_ws, size_t ws_size,
                              hipStream_t stream) {
    const float* X    = (const float*)d_in[0];
    const int*   mask = (const int*)d_in[1];
    const float* Wq   = (const float*)d_in[2];
    const float* bq   = (const float*)d_in[3];
    const float* Wk   = (const float*)d_in[4];
    const float* bk   = (const float*)d_in[5];
    const float* Wv   = (const float*)d_in[6];
    const float* bv   = (const float*)d_in[7];
    float* out = (float*)d_out;

    char* p = (char*)d_ws;
    bf16* Qd  = (bf16*)p;  p += (size_t)B_ * S_ * H_ * 2;
    bf16* Kd  = (bf16*)p;  p += (size_t)B_ * S_ * H_ * 2;
    bf16* Vtd = (bf16*)p;  p += (size_t)B_ * S_ * H_ * 2;
    bf16* Wc  = (bf16*)p;  p += (size_t)192 * 1024 * 2;
    float* bc = (float*)p; p += 192 * 4;

    conv_w<<<dim3(768), dim3(256), 0, stream>>>(Wq, bq, Wk, bk, Wv, bv, Wc, bc);
    qkv_gemm<<<dim3(512), dim3(256), 0, stream>>>(X, Wc, bc, Qd, Kd, Vtd);
    attn<<<dim3(256), dim3(256), 0, stream>>>(Qd, Kd, Vtd, mask, out);
}

// Round 2
// 277.315 us; speedup vs baseline: 1.5575x; 1.5575x over previous
//
#include <hip/hip_runtime.h>

typedef __bf16 bf16;
typedef bf16 bf16x4 __attribute__((ext_vector_type(4)));
typedef bf16 bf16x8 __attribute__((ext_vector_type(8)));
typedef float floatx4 __attribute__((ext_vector_type(4)));
typedef unsigned int u32;

#define B_ 8
#define S_ 2048
#define I_ 1024
#define H_ 64
#define NEG_INF_ -1000000000.0f

// async global->LDS 16B/lane: LDS dst = wave-uniform base + lane*16
__device__ __forceinline__ void async_cp16(bf16* lds_base, const bf16* g_base, int lane) {
    __builtin_amdgcn_global_load_lds(
        (const __attribute__((address_space(1))) u32*)(g_base + lane * 8),
        (__attribute__((address_space(3))) u32*)lds_base, 16, 0, 0);
}

// ---------------- Kernel A: fold scale + convert weights to bf16 ----------------
__global__ void conv_w(const float* __restrict__ Wq, const float* __restrict__ bq,
                       const float* __restrict__ Wk, const float* __restrict__ bk,
                       const float* __restrict__ Wv, const float* __restrict__ bv,
                       bf16* __restrict__ Wc, float* __restrict__ bc) {
    int idx = blockIdx.x * 256 + threadIdx.x;   // 0 .. 192*1024-1
    int n = idx >> 10, i = idx & 1023;
    float v;
    if (n < 64)       v = Wq[n * I_ + i] * 0.125f;
    else if (n < 128) v = Wk[(n - 64) * I_ + i];
    else              v = Wv[(n - 128) * I_ + i];
    Wc[idx] = (bf16)v;
    if (idx < 192) {
        float bb = (idx < 64) ? bq[idx] * 0.125f
                 : (idx < 128) ? bk[idx - 64] : bv[idx - 128];
        bc[idx] = bb;
    }
}

// ---------------- Kernel B: QKV projection GEMM ----------------
// Grid 1024 (M-tile 16), block 256 (4 waves). Wave w: N cols w*48..w*48+47. BK=64.
// Outputs: Qd[b][s][h] bf16 (Q pre-scaled 1/8);
//          Kd2[b][hc][s][8h] bf16 (h chunked by 8);
//          Vt2[b][kc][h][8k] bf16 (k chunked by 8).
__global__ __launch_bounds__(256, 4) void qkv_gemm(const float* __restrict__ X,
                                                   const bf16* __restrict__ Wc,
                                                   const float* __restrict__ bc,
                                                   bf16* __restrict__ Qd,
                                                   bf16* __restrict__ Kd2,
                                                   bf16* __restrict__ Vt2) {
    __shared__ __align__(16) bf16 Xs[16 * 72];
    __shared__ __align__(16) bf16 Ws[192 * 72];

    int tid = threadIdx.x;
    int w = tid >> 6, lane = tid & 63;
    int n = lane & 15, g = lane >> 4;
    int m0 = blockIdx.x * 16;

    floatx4 zero4 = {0.0f, 0.0f, 0.0f, 0.0f};
    floatx4 acc[3];
#pragma unroll
    for (int t = 0; t < 3; ++t) acc[t] = zero4;

    int xrow = tid >> 4, xq = tid & 15;   // 16 rows x 16 float4
    const float* xsrc = X + (size_t)(m0 + xrow) * I_ + xq * 4;
    bf16* xdst = Xs + xrow * 72 + xq * 4;

    for (int kk0 = 0; kk0 < I_; kk0 += 64) {
        float4 xv = *(const float4*)(xsrc + kk0);
        bf16x4 xb;
        xb[0] = (bf16)xv.x; xb[1] = (bf16)xv.y; xb[2] = (bf16)xv.z; xb[3] = (bf16)xv.w;
        *(bf16x4*)xdst = xb;
        // W tile 192x64 bf16 = 1536 16B chunks, 6/thread
#pragma unroll
        for (int i = 0; i < 6; ++i) {
            int cid = i * 256 + tid;
            int wrow = cid >> 3, wc = cid & 7;
            *(bf16x8*)(Ws + wrow * 72 + wc * 8) =
                *(const bf16x8*)(Wc + (size_t)wrow * I_ + kk0 + wc * 8);
        }
        __syncthreads();
#pragma unroll
        for (int ks = 0; ks < 2; ++ks) {
            bf16x8 xa = *(bf16x8*)(Xs + n * 72 + ks * 32 + g * 8);
#pragma unroll
            for (int nt = 0; nt < 3; ++nt) {
                bf16x8 wb = *(bf16x8*)(Ws + (w * 48 + nt * 16 + n) * 72 + ks * 32 + g * 8);
                acc[nt] = __builtin_amdgcn_mfma_f32_16x16x32_bf16(xa, wb, acc[nt], 0, 0, 0);
            }
        }
        __syncthreads();
    }

    // epilogue: C/D layout col=lane&15, row=g*4+r
    int b = m0 >> 11;
    int sb = (m0 & 2047) + g * 4;
#pragma unroll
    for (int nt = 0; nt < 3; ++nt) {
        int ng = w * 48 + nt * 16 + n;
        float bias = bc[ng];
        if (ng < 64) {
#pragma unroll
            for (int r = 0; r < 4; ++r)
                Qd[(size_t)(b * S_ + sb + r) * H_ + ng] = (bf16)(acc[nt][r] + bias);
        } else if (ng < 128) {
            int hc = (ng - 64) >> 3, j = (ng - 64) & 7;
#pragma unroll
            for (int r = 0; r < 4; ++r)
                Kd2[((size_t)(b * 8 + hc) * S_ + sb + r) * 8 + j] = (bf16)(acc[nt][r] + bias);
        } else {
            int hh = ng - 128, kc = sb >> 3, jj = sb & 7;
            bf16x4 pk;
#pragma unroll
            for (int r = 0; r < 4; ++r) pk[r] = (bf16)(acc[nt][r] + bias);
            *(bf16x4*)(Vt2 + ((size_t)(b * 256 + kc) * 64 + hh) * 8 + jj) = pk;
        }
    }
}

// ---------------- Kernel C: flash attention, k-split x4 ----------------
// Grid 1024: bid = (b*32+qt)*4 + ksp. Block 256 (4 waves), q-tile 64, 512 k-cols/block.
// LDS: regA = K chunks (8 x 1040, stride == 8 mod 32 dw -> 2-way banks) aliased with
// P (64 x 136); Vs = 16 k-chunks x 528. K/V staged via global_load_lds (no regs).
__global__ __launch_bounds__(256, 4) void attn(const bf16* __restrict__ Qd,
                                               const bf16* __restrict__ Kd2,
                                               const bf16* __restrict__ Vt2,
                                               const int* __restrict__ mask,
                                               float* __restrict__ po,
                                               float* __restrict__ pml) {
    __shared__ __align__(16) bf16 regA[8704];   // Ks (8*1040=8320) / Ps (64*136=8704)
    __shared__ __align__(16) bf16 Vs[16 * 528]; // 8448

    int tid = threadIdx.x;
    int w = tid >> 6, lane = tid & 63;
    int n = lane & 15, g = lane >> 4;
    int bid = blockIdx.x;
    int ksp = bid & 3;
    int qt = (bid >> 2) & 31;
    int b = bid >> 7;
    int q0 = qt * 64;

    // Q A-frags (pre-scaled): A[m=lane&15][kk=g*8+j]
    const bf16* qptr = Qd + (size_t)(b * S_ + q0 + w * 16 + n) * H_ + g * 8;
    bf16x8 qa0 = *(const bf16x8*)qptr;
    bf16x8 qa1 = *(const bf16x8*)(qptr + 32);

    floatx4 zero4 = {0.0f, 0.0f, 0.0f, 0.0f};
    floatx4 o[4];
#pragma unroll
    for (int t = 0; t < 4; ++t) o[t] = zero4;
    float m_i[4], l_i[4];
#pragma unroll
    for (int r = 0; r < 4; ++r) { m_i[r] = -INFINITY; l_i[r] = 0.0f; }

    for (int kt = ksp * 4; kt < ksp * 4 + 4; ++kt) {
        // ---- async stage K (8 h-chunks x 2KB) and V (16 k-chunks x 1KB) ----
#pragma unroll
        for (int j = 0; j < 4; ++j) {
            int hc = w * 2 + (j >> 1), p = j & 1;
            async_cp16(regA + hc * 1040 + p * 512,
                       Kd2 + ((size_t)(b * 8 + hc) * S_ + kt * 128 + p * 64) * 8, lane);
        }
#pragma unroll
        for (int j = 0; j < 4; ++j) {
            int kcl = w * 4 + j;
            async_cp16(Vs + kcl * 528,
                       Vt2 + ((size_t)(b * 256 + kt * 16 + kcl) * 64) * 8, lane);
        }
        // ---- batch mask prefetch (32 dwords in flight; drains with staging) ----
        const int* mb = mask + (size_t)(b * S_ + q0 + w * 16 + g * 4) * S_ + kt * 128 + n;
        int mreg[4][8];
#pragma unroll
        for (int r = 0; r < 4; ++r)
#pragma unroll
            for (int nt = 0; nt < 8; ++nt)
                mreg[r][nt] = mb[(size_t)r * S_ + nt * 16];
        __syncthreads();   // b1: staging + masks done

        // ---- S = Q K^T : B[n=k-col][kk=h], h-chunk = g / 4+g ----
        floatx4 s[8];
#pragma unroll
        for (int nt = 0; nt < 8; ++nt) {
            floatx4 a = zero4;
            a = __builtin_amdgcn_mfma_f32_16x16x32_bf16(
                    qa0, *(const bf16x8*)(regA + g * 1040 + (nt * 16 + n) * 8), a, 0, 0, 0);
            a = __builtin_amdgcn_mfma_f32_16x16x32_bf16(
                    qa1, *(const bf16x8*)(regA + (4 + g) * 1040 + (nt * 16 + n) * 8), a, 0, 0, 0);
            s[nt] = a;
        }

        // ---- mask + online softmax (rows = g*4+r, shared by 16-lane group) ----
#pragma unroll
        for (int r = 0; r < 4; ++r)
#pragma unroll
            for (int nt = 0; nt < 8; ++nt)
                if (mreg[r][nt] == 0) s[nt][r] = NEG_INF_;
#pragma unroll
        for (int r = 0; r < 4; ++r) {
            float tm = s[0][r];
#pragma unroll
            for (int nt = 1; nt < 8; ++nt) tm = fmaxf(tm, s[nt][r]);
#pragma unroll
            for (int off = 1; off < 16; off <<= 1) tm = fmaxf(tm, __shfl_xor(tm, off, 64));
            float mn = fmaxf(m_i[r], tm);
            float alpha = __expf(m_i[r] - mn);   // first iter: exp(-inf)=0
            m_i[r] = mn;
            float rs = 0.0f;
#pragma unroll
            for (int nt = 0; nt < 8; ++nt) {
                float p = __expf(s[nt][r] - mn);
                s[nt][r] = p;
                rs += p;
            }
#pragma unroll
            for (int off = 1; off < 16; off <<= 1) rs += __shfl_xor(rs, off, 64);
            l_i[r] = l_i[r] * alpha + rs;
#pragma unroll
            for (int ht = 0; ht < 4; ++ht) o[ht][r] *= alpha;
        }
        __syncthreads();   // b2: all waves done reading K region

        // ---- P: C-layout -> LDS (aliased over K region) ----
#pragma unroll
        for (int r = 0; r < 4; ++r)
#pragma unroll
            for (int nt = 0; nt < 8; ++nt)
                regA[(w * 16 + g * 4 + r) * 136 + nt * 16 + n] = (bf16)s[nt][r];
        __syncthreads();   // b3: P visible

        // ---- O += P V : A from Ps, B from Vs k-chunks ----
#pragma unroll
        for (int k0 = 0; k0 < 4; ++k0) {
            bf16x8 pa = *(bf16x8*)(regA + (w * 16 + n) * 136 + k0 * 32 + g * 8);
#pragma unroll
            for (int ht = 0; ht < 4; ++ht) {
                bf16x8 vb = *(bf16x8*)(Vs + (k0 * 4 + g) * 528 + (ht * 16 + n) * 8);
                o[ht] = __builtin_amdgcn_mfma_f32_16x16x32_bf16(pa, vb, o[ht], 0, 0, 0);
            }
        }
        __syncthreads();   // b4: PV reads done before next staging overwrites
    }

    // ---- partials: unnormalized o + (m,l) per q-row ----
    float* pb = po + (size_t)bid * 4096;
#pragma unroll
    for (int ht = 0; ht < 4; ++ht)
#pragma unroll
        for (int r = 0; r < 4; ++r)
            pb[(w * 16 + g * 4 + r) * 64 + ht * 16 + n] = o[ht][r];
    if (n == 0) {
#pragma unroll
        for (int r = 0; r < 4; ++r) {
            pml[(size_t)bid * 128 + w * 16 + g * 4 + r] = m_i[r];
            pml[(size_t)bid * 128 + 64 + w * 16 + g * 4 + r] = l_i[r];
        }
    }
}

// ---------------- Kernel D: merge 4 k-split partials ----------------
__global__ __launch_bounds__(256) void reduce_o(const float* __restrict__ po,
                                                const float* __restrict__ pml,
                                                float* __restrict__ out) {
    int idx = blockIdx.x * 256 + threadIdx.x;   // (q,h): 16384*64
    int h = idx & 63, q = idx >> 6;
    int b = q >> 11, qq = q & 2047;
    int qt = qq >> 6, ql = qq & 63;
    int bid0 = (b * 32 + qt) * 4;
    float mj[4], lj[4], M = -INFINITY;
#pragma unroll
    for (int j = 0; j < 4; ++j) {
        mj[j] = pml[(size_t)(bid0 + j) * 128 + ql];
        lj[j] = pml[(size_t)(bid0 + j) * 128 + 64 + ql];
        M = fmaxf(M, mj[j]);
    }
    float num = 0.0f, den = 0.0f;
#pragma unroll
    for (int j = 0; j < 4; ++j) {
        float sc = __expf(mj[j] - M);   // mj finite always (scores >= -1e9)
        den += lj[j] * sc;
        num += po[(size_t)(bid0 + j) * 4096 + ql * 64 + h] * sc;
    }
    out[(size_t)q * 64 + h] = num / den;
}

extern "C" void kernel_launch(void* const* d_in, const int* in_sizes, int n_in,
                              void* d_out, int out_size, void* d_ws, size_t ws_size,
                              hipStream_t stream) {
    const float* X    = (const float*)d_in[0];
    const int*   mask = (const int*)d_in[1];
    const float* Wq   = (const float*)d_in[2];
    const float* bq   = (const float*)d_in[3];
    const float* Wk   = (const float*)d_in[4];
    const float* bk   = (const float*)d_in[5];
    const float* Wv   = (const float*)d_in[6];
    const float* bv   = (const float*)d_in[7];
    float* out = (float*)d_out;

    char* p = (char*)d_ws;
    bf16* Qd   = (bf16*)p;  p += (size_t)B_ * S_ * H_ * 2;      // 2 MB
    bf16* Kd2  = (bf16*)p;  p += (size_t)B_ * S_ * H_ * 2;      // 2 MB
    bf16* Vt2  = (bf16*)p;  p += (size_t)B_ * S_ * H_ * 2;      // 2 MB
    bf16* Wc   = (bf16*)p;  p += (size_t)192 * 1024 * 2;        // 384 KB
    float* bc  = (float*)p; p += 1024;
    float* po  = (float*)p; p += (size_t)1024 * 4096 * 4;       // 16 MB
    float* pml = (float*)p; p += (size_t)1024 * 128 * 4;        // 512 KB

    conv_w<<<dim3(768), dim3(256), 0, stream>>>(Wq, bq, Wk, bk, Wv, bv, Wc, bc);
    qkv_gemm<<<dim3(1024), dim3(256), 0, stream>>>(X, Wc, bc, Qd, Kd2, Vt2);
    attn<<<dim3(1024), dim3(256), 0, stream>>>(Qd, Kd2, Vt2, mask, po, pml);
    reduce_o<<<dim3(4096), dim3(256), 0, stream>>>(po, pml, out);
}

// Round 3
// 267.067 us; speedup vs baseline: 1.6173x; 1.0384x over previous
//
#include <hip/hip_runtime.h>

typedef __bf16 bf16;
typedef bf16 bf16x4 __attribute__((ext_vector_type(4)));
typedef bf16 bf16x8 __attribute__((ext_vector_type(8)));
typedef float floatx4 __attribute__((ext_vector_type(4)));
typedef unsigned int u32;

#define B_ 8
#define S_ 2048
#define I_ 1024
#define H_ 64
#define NEG_INF_ -1000000000.0f

// async global->LDS 16B/lane: LDS dst = wave-uniform base + lane*16
__device__ __forceinline__ void async_cp16(bf16* lds_base, const bf16* g_base, int lane) {
    __builtin_amdgcn_global_load_lds(
        (const __attribute__((address_space(1))) u32*)(g_base + lane * 8),
        (__attribute__((address_space(3))) u32*)lds_base, 16, 0, 0);
}

// ---------------- Kernel A: fold scale + convert + PACK weights ----------------
// Wc2: 8 K-slabs, each [192 rows][136 cols] bf16 (cols 128..135 pad) — exact LDS
// image so qkv can stage slabs with lane-linear global_load_lds.
// row 0-63 = Wq*0.125, 64-127 = Wk, 128-191 = Wv.
__global__ void conv_w(const float* __restrict__ Wq, const float* __restrict__ bq,
                       const float* __restrict__ Wk, const float* __restrict__ bk,
                       const float* __restrict__ Wv, const float* __restrict__ bv,
                       bf16* __restrict__ Wc2, float* __restrict__ bc) {
    int idx = blockIdx.x * 256 + threadIdx.x;   // 0 .. 192*1024-1
    int n = idx >> 10, i = idx & 1023;
    float v;
    if (n < 64)       v = Wq[n * I_ + i] * 0.125f;
    else if (n < 128) v = Wk[(n - 64) * I_ + i];
    else              v = Wv[(n - 128) * I_ + i];
    int s = i >> 7, kl = i & 127;
    Wc2[(size_t)s * 26112 + n * 136 + kl] = (bf16)v;
    if (idx < 192) {
        float bb = (idx < 64) ? bq[idx] * 0.125f
                 : (idx < 128) ? bk[idx - 64] : bv[idx - 128];
        bc[idx] = bb;
    }
}

// ---------------- Kernel B: QKV projection GEMM ----------------
// Grid 512 (M-tile 32), block 256 (4 waves), BK=128 (8 iters).
// Wave w: m-sub = w&1 (16 rows), n-group = (w>>1)*96 (6 n-tiles). 24 MFMA/wave/iter.
// W staged via global_load_lds from pre-packed slabs; X via float4+cvt (read once).
// Outputs: Qd[b][s][h] (pre-scaled 1/8); Kd2[b][hc][s][8h]; Vt2[b][kc][h][8k].
__global__ __launch_bounds__(256, 2) void qkv_gemm(const float* __restrict__ X,
                                                   const bf16* __restrict__ Wc2,
                                                   const float* __restrict__ bc,
                                                   bf16* __restrict__ Qd,
                                                   bf16* __restrict__ Kd2,
                                                   bf16* __restrict__ Vt2) {
    __shared__ __align__(16) bf16 Xs[32 * 136];   // 8704 B
    __shared__ __align__(16) bf16 Ws[26112];      // 52224 B (192 x 136)

    int tid = threadIdx.x;
    int w = tid >> 6, lane = tid & 63;
    int n = lane & 15, g = lane >> 4;
    int m0 = blockIdx.x * 32;
    int mt = w & 1, nh = (w >> 1) * 96;

    floatx4 zero4 = {0.0f, 0.0f, 0.0f, 0.0f};
    floatx4 acc[6];
#pragma unroll
    for (int t = 0; t < 6; ++t) acc[t] = zero4;

    // X staging map: thread t covers 16 consecutive floats (64 B) of the 32x128 tile
    int xrow = tid >> 3, xcb = (tid & 7) * 16;    // row 0..31, col base 0..112
    const float* xsrc = X + (size_t)(m0 + xrow) * I_ + xcb;
    bf16* xdst = Xs + xrow * 136 + xcb;

    for (int s = 0; s < 8; ++s) {
        // ---- stage X slab 32x128 fp32 -> bf16 (VGPR path, 4 float4/thread) ----
        const float* xp = xsrc + s * 128;
        float4 x0 = *(const float4*)(xp);
        float4 x1 = *(const float4*)(xp + 4);
        float4 x2 = *(const float4*)(xp + 8);
        float4 x3 = *(const float4*)(xp + 12);
        // ---- stage W slab 192x128 (+pad) via async, 51 x 1KB insts ----
#pragma unroll
        for (int i = 0; i < 13; ++i) {
            int inst = i * 4 + w;
            if (inst < 51)
                async_cp16(Ws + inst * 512, Wc2 + (size_t)s * 26112 + inst * 512, lane);
        }
        bf16x8 b0, b1;
        b0[0] = (bf16)x0.x; b0[1] = (bf16)x0.y; b0[2] = (bf16)x0.z; b0[3] = (bf16)x0.w;
        b0[4] = (bf16)x1.x; b0[5] = (bf16)x1.y; b0[6] = (bf16)x1.z; b0[7] = (bf16)x1.w;
        b1[0] = (bf16)x2.x; b1[1] = (bf16)x2.y; b1[2] = (bf16)x2.z; b1[3] = (bf16)x2.w;
        b1[4] = (bf16)x3.x; b1[5] = (bf16)x3.y; b1[6] = (bf16)x3.z; b1[7] = (bf16)x3.w;
        *(bf16x8*)xdst = b0;
        *(bf16x8*)(xdst + 8) = b1;
        __syncthreads();

        // ---- compute: 4 k-steps of 32 ----
#pragma unroll
        for (int ks = 0; ks < 4; ++ks) {
            bf16x8 xa = *(bf16x8*)(Xs + (mt * 16 + n) * 136 + ks * 32 + g * 8);
#pragma unroll
            for (int nt = 0; nt < 6; ++nt) {
                bf16x8 wb = *(bf16x8*)(Ws + (nh + nt * 16 + n) * 136 + ks * 32 + g * 8);
                acc[nt] = __builtin_amdgcn_mfma_f32_16x16x32_bf16(xa, wb, acc[nt], 0, 0, 0);
            }
        }
        __syncthreads();
    }

    // ---- epilogue: C/D layout col=lane&15, row=g*4+r ----
    int b = m0 >> 11;
    int sb = (m0 & 2047) + mt * 16 + g * 4;
#pragma unroll
    for (int nt = 0; nt < 6; ++nt) {
        int ng = nh + nt * 16 + n;
        float bias = bc[ng];
        if (ng < 64) {
#pragma unroll
            for (int r = 0; r < 4; ++r)
                Qd[(size_t)(b * S_ + sb + r) * H_ + ng] = (bf16)(acc[nt][r] + bias);
        } else if (ng < 128) {
            int hc = (ng - 64) >> 3, j = (ng - 64) & 7;
#pragma unroll
            for (int r = 0; r < 4; ++r)
                Kd2[((size_t)(b * 8 + hc) * S_ + sb + r) * 8 + j] = (bf16)(acc[nt][r] + bias);
        } else {
            int hh = ng - 128, kc = sb >> 3, jj = sb & 7;
            bf16x4 pk;
#pragma unroll
            for (int r = 0; r < 4; ++r) pk[r] = (bf16)(acc[nt][r] + bias);
            *(bf16x4*)(Vt2 + ((size_t)(b * 256 + kc) * 64 + hh) * 8 + jj) = pk;
        }
    }
}

// ---------------- Kernel C: flash attention, k-split x4 ----------------
// Grid 1024: bid = (b*32+qt)*4 + ksp. Block 256 (4 waves), q-tile 64, 512 k/block.
// Mask loads (HBM) issued BEFORE async K/V staging (L2) so one barrier drain
// overlaps both latencies.
__global__ __launch_bounds__(256, 4) void attn(const bf16* __restrict__ Qd,
                                               const bf16* __restrict__ Kd2,
                                               const bf16* __restrict__ Vt2,
                                               const int* __restrict__ mask,
                                               float* __restrict__ po,
                                               float* __restrict__ pml) {
    __shared__ __align__(16) bf16 regA[8704];   // Ks (8*1040) aliased with Ps (64*136)
    __shared__ __align__(16) bf16 Vs[16 * 528];

    int tid = threadIdx.x;
    int w = tid >> 6, lane = tid & 63;
    int n = lane & 15, g = lane >> 4;
    int bid = blockIdx.x;
    int ksp = bid & 3;
    int qt = (bid >> 2) & 31;
    int b = bid >> 7;
    int q0 = qt * 64;

    const bf16* qptr = Qd + (size_t)(b * S_ + q0 + w * 16 + n) * H_ + g * 8;
    bf16x8 qa0 = *(const bf16x8*)qptr;
    bf16x8 qa1 = *(const bf16x8*)(qptr + 32);

    floatx4 zero4 = {0.0f, 0.0f, 0.0f, 0.0f};
    floatx4 o[4];
#pragma unroll
    for (int t = 0; t < 4; ++t) o[t] = zero4;
    float m_i[4], l_i[4];
#pragma unroll
    for (int r = 0; r < 4; ++r) { m_i[r] = -INFINITY; l_i[r] = 0.0f; }

    for (int kt = ksp * 4; kt < ksp * 4 + 4; ++kt) {
        // ---- batch mask loads first (longest latency: HBM) ----
        const int* mb = mask + (size_t)(b * S_ + q0 + w * 16 + g * 4) * S_ + kt * 128 + n;
        int mreg[4][8];
#pragma unroll
        for (int r = 0; r < 4; ++r)
#pragma unroll
            for (int nt = 0; nt < 8; ++nt)
                mreg[r][nt] = mb[(size_t)r * S_ + nt * 16];
        // ---- async stage K (8 h-chunks x 2KB) and V (16 k-chunks x 1KB) ----
#pragma unroll
        for (int j = 0; j < 4; ++j) {
            int hc = w * 2 + (j >> 1), p = j & 1;
            async_cp16(regA + hc * 1040 + p * 512,
                       Kd2 + ((size_t)(b * 8 + hc) * S_ + kt * 128 + p * 64) * 8, lane);
        }
#pragma unroll
        for (int j = 0; j < 4; ++j) {
            int kcl = w * 4 + j;
            async_cp16(Vs + kcl * 528,
                       Vt2 + ((size_t)(b * 256 + kt * 16 + kcl) * 64) * 8, lane);
        }
        __syncthreads();   // b1: staging + masks done

        // ---- S = Q K^T ----
        floatx4 s[8];
#pragma unroll
        for (int nt = 0; nt < 8; ++nt) {
            floatx4 a = zero4;
            a = __builtin_amdgcn_mfma_f32_16x16x32_bf16(
                    qa0, *(const bf16x8*)(regA + g * 1040 + (nt * 16 + n) * 8), a, 0, 0, 0);
            a = __builtin_amdgcn_mfma_f32_16x16x32_bf16(
                    qa1, *(const bf16x8*)(regA + (4 + g) * 1040 + (nt * 16 + n) * 8), a, 0, 0, 0);
            s[nt] = a;
        }

        // ---- mask + online softmax ----
#pragma unroll
        for (int r = 0; r < 4; ++r)
#pragma unroll
            for (int nt = 0; nt < 8; ++nt)
                if (mreg[r][nt] == 0) s[nt][r] = NEG_INF_;
#pragma unroll
        for (int r = 0; r < 4; ++r) {
            float tm = s[0][r];
#pragma unroll
            for (int nt = 1; nt < 8; ++nt) tm = fmaxf(tm, s[nt][r]);
#pragma unroll
            for (int off = 1; off < 16; off <<= 1) tm = fmaxf(tm, __shfl_xor(tm, off, 64));
            float mn = fmaxf(m_i[r], tm);
            float alpha = __expf(m_i[r] - mn);
            m_i[r] = mn;
            float rs = 0.0f;
#pragma unroll
            for (int nt = 0; nt < 8; ++nt) {
                float p = __expf(s[nt][r] - mn);
                s[nt][r] = p;
                rs += p;
            }
#pragma unroll
            for (int off = 1; off < 16; off <<= 1) rs += __shfl_xor(rs, off, 64);
            l_i[r] = l_i[r] * alpha + rs;
#pragma unroll
            for (int ht = 0; ht < 4; ++ht) o[ht][r] *= alpha;
        }
        __syncthreads();   // b2: K-region reads done

        // ---- P: C-layout -> LDS (aliased over K region) ----
#pragma unroll
        for (int r = 0; r < 4; ++r)
#pragma unroll
            for (int nt = 0; nt < 8; ++nt)
                regA[(w * 16 + g * 4 + r) * 136 + nt * 16 + n] = (bf16)s[nt][r];
        __syncthreads();   // b3: P visible

        // ---- O += P V ----
#pragma unroll
        for (int k0 = 0; k0 < 4; ++k0) {
            bf16x8 pa = *(bf16x8*)(regA + (w * 16 + n) * 136 + k0 * 32 + g * 8);
#pragma unroll
            for (int ht = 0; ht < 4; ++ht) {
                bf16x8 vb = *(bf16x8*)(Vs + (k0 * 4 + g) * 528 + (ht * 16 + n) * 8);
                o[ht] = __builtin_amdgcn_mfma_f32_16x16x32_bf16(pa, vb, o[ht], 0, 0, 0);
            }
        }
        __syncthreads();   // b4: PV reads done before next staging
    }

    float* pb = po + (size_t)bid * 4096;
#pragma unroll
    for (int ht = 0; ht < 4; ++ht)
#pragma unroll
        for (int r = 0; r < 4; ++r)
            pb[(w * 16 + g * 4 + r) * 64 + ht * 16 + n] = o[ht][r];
    if (n == 0) {
#pragma unroll
        for (int r = 0; r < 4; ++r) {
            pml[(size_t)bid * 128 + w * 16 + g * 4 + r] = m_i[r];
            pml[(size_t)bid * 128 + 64 + w * 16 + g * 4 + r] = l_i[r];
        }
    }
}

// ---------------- Kernel D: merge 4 k-split partials ----------------
__global__ __launch_bounds__(256) void reduce_o(const float* __restrict__ po,
                                                const float* __restrict__ pml,
                                                float* __restrict__ out) {
    int idx = blockIdx.x * 256 + threadIdx.x;   // (q,h): 16384*64
    int h = idx & 63, q = idx >> 6;
    int b = q >> 11, qq = q & 2047;
    int qt = qq >> 6, ql = qq & 63;
    int bid0 = (b * 32 + qt) * 4;
    float mj[4], lj[4], M = -INFINITY;
#pragma unroll
    for (int j = 0; j < 4; ++j) {
        mj[j] = pml[(size_t)(bid0 + j) * 128 + ql];
        lj[j] = pml[(size_t)(bid0 + j) * 128 + 64 + ql];
        M = fmaxf(M, mj[j]);
    }
    float num = 0.0f, den = 0.0f;
#pragma unroll
    for (int j = 0; j < 4; ++j) {
        float sc = __expf(mj[j] - M);
        den += lj[j] * sc;
        num += po[(size_t)(bid0 + j) * 4096 + ql * 64 + h] * sc;
    }
    out[(size_t)q * 64 + h] = num / den;
}

extern "C" void kernel_launch(void* const* d_in, const int* in_sizes, int n_in,
                              void* d_out, int out_size, void* d_ws, size_t ws_size,
                              hipStream_t stream) {
    const float* X    = (const float*)d_in[0];
    const int*   mask = (const int*)d_in[1];
    const float* Wq   = (const float*)d_in[2];
    const float* bq   = (const float*)d_in[3];
    const float* Wk   = (const float*)d_in[4];
    const float* bk   = (const float*)d_in[5];
    const float* Wv   = (const float*)d_in[6];
    const float* bv   = (const float*)d_in[7];
    float* out = (float*)d_out;

    char* p = (char*)d_ws;
    bf16* Qd   = (bf16*)p;  p += (size_t)B_ * S_ * H_ * 2;      // 2 MB
    bf16* Kd2  = (bf16*)p;  p += (size_t)B_ * S_ * H_ * 2;      // 2 MB
    bf16* Vt2  = (bf16*)p;  p += (size_t)B_ * S_ * H_ * 2;      // 2 MB
    bf16* Wc2  = (bf16*)p;  p += (size_t)8 * 26112 * 2;         // 417 KB packed W
    float* bc  = (float*)p; p += 1024;
    float* po  = (float*)p; p += (size_t)1024 * 4096 * 4;       // 16 MB
    float* pml = (float*)p; p += (size_t)1024 * 128 * 4;        // 512 KB

    conv_w<<<dim3(768), dim3(256), 0, stream>>>(Wq, bq, Wk, bk, Wv, bv, Wc2, bc);
    qkv_gemm<<<dim3(512), dim3(256), 0, stream>>>(X, Wc2, bc, Qd, Kd2, Vt2);
    attn<<<dim3(1024), dim3(256), 0, stream>>>(Qd, Kd2, Vt2, mask, po, pml);
    reduce_o<<<dim3(4096), dim3(256), 0, stream>>>(po, pml, out);
}